// Round 1
// baseline (16073.645 us; speedup 1.0000x reference)
//
#include <hip/hip_runtime.h>
#include <hip/hip_fp16.h>

// AlternatingForecastModel: 4096-step LSTM (B=256,H=256) with anomaly memory blend.
// Design: 1 batch per CU (256 blocks x 256 threads). Weights in f16:
//   - 23 pairs/row/slice in VGPRs (368 regs/thread)
//   - 9 pairs/row/slice in LDS (144KB), [chunk][wave][lane] layout -> conflict-free b128
// k-split: lane s=tid&3 owns h-cols [64s,64s+64); 2-step shfl_xor butterfly reduce.
// Thread tid owns hidden unit u=tid (rows {u,256+u,512+u,768+u}); c and the W=10
// ring buffer live in registers (always-shift-append + count-indexed weight table).
// Anomaly flags (batch-global, input-only) precomputed by pre-kernel as packed bits.

#define Bb 256
#define Tt 4096
#define Ff 16
#define Hh 256
#define CV_PAIRS 23
#define SLICE_PAIRS 32
#define LDS_PAIRS (SLICE_PAIRS - CV_PAIRS)   // 9
#define NCHUNK (4 * LDS_PAIRS)               // 36 x 16B chunks per thread
#define MEM_DECAY 0.3f
#define SMOOTH 0.1f

typedef _Float16 h2v __attribute__((ext_vector_type(2)));

__device__ __forceinline__ uint32_t pkh2(float a, float b) {
    __half2 h = __floats2half2_rn(a, b);
    return __builtin_bit_cast(uint32_t, h);
}

__device__ __forceinline__ float dot2f(uint32_t a, uint32_t b, float c) {
#if __has_builtin(__builtin_amdgcn_fdot2)
    return __builtin_amdgcn_fdot2(__builtin_bit_cast(h2v, a),
                                  __builtin_bit_cast(h2v, b), c, false);
#else
    h2v x = __builtin_bit_cast(h2v, a), y = __builtin_bit_cast(h2v, b);
    return c + (float)x[0] * (float)y[0] + (float)x[1] * (float)y[1];
#endif
}

__device__ __forceinline__ float sigm_(float x) { return 1.0f / (1.0f + __expf(-x)); }
__device__ __forceinline__ float tanh_(float x) { return 1.0f - 2.0f / (__expf(2.0f * x) + 1.0f); }

// ---------------- pre-kernel: packed anomaly bits (128 u32 words) ----------------
__global__ void __launch_bounds__(256) anom_kernel(const float* __restrict__ x,
                                                   uint32_t* __restrict__ anomw) {
    // grid 64: block k covers t in [64k,64k+64). thread j: tsub=j&63, bgrp=j>>6.
    __shared__ uint32_t part[4][64];
    const int k = blockIdx.x, j = threadIdx.x;
    const int tsub = j & 63, bg = j >> 6;
    const int t = k * 64 + tsub;
    uint32_t a = 0;
    for (int b = bg * 64; b < bg * 64 + 64; ++b)
        a |= (x[((size_t)b * Tt + t) * Ff + (Ff - 1)] != 0.0f) ? 1u : 0u;
    part[bg][tsub] = a;
    __syncthreads();
    if (j < 64) {
        uint32_t any = part[0][j] | part[1][j] | part[2][j] | part[3][j];
        unsigned long long m = __ballot(any != 0);   // wave 0, lane j <-> t=64k+j
        if (j == 0) {
            anomw[2 * k]     = (uint32_t)(m & 0xffffffffull);
            anomw[2 * k + 1] = (uint32_t)(m >> 32);
        }
    }
}

// ---------------- main kernel ----------------
__global__ void __launch_bounds__(256, 1) lstm_kernel(
    const float* __restrict__ x,
    const float* __restrict__ W_ih, const float* __restrict__ b_ih,
    const float* __restrict__ W_hh, const float* __restrict__ b_hh,
    const float* __restrict__ W_out, const float* __restrict__ b_out,
    const uint32_t* __restrict__ anomw,
    float* __restrict__ out)
{
    __shared__ uint32_t lds_w[NCHUNK * 1024];   // 147456 B, [chunk][wave][lane][4dw]
    __shared__ uint32_t xst[64 * 8];            // 2048 B: 64 steps x 8 f16-pairs
    __shared__ uint32_t hbuf_u[2 * 128];        // 1024 B: dbuf h as f16 pairs
    __shared__ uint32_t abits[128];             // 512 B packed anomaly bits
    __shared__ float    w2[11][10];             // softmax-weight table by count
    __shared__ float    outp[2][4];             // per-wave out partials (dbuf)

    const int tid = threadIdx.x;
    const int b   = blockIdx.x;
    const int g   = tid >> 2, s = tid & 3;       // unit-group, k-slice
    const uint32_t wbase = (uint32_t)((tid >> 6) * 256 + (tid & 63) * 4); // dword idx in chunk

    // ---- persistent VGPR weights: wv[r][k] = W_hh[row(r)][64s+2k .. +1] as f16 pair
    // r = u*4 + G  (u=r>>2 unit-offset, G=r&3 gate), row = 256G + 4g + u
    uint32_t wv[16][CV_PAIRS];
#pragma unroll
    for (int r = 0; r < 16; ++r) {
        const int row = ((r & 3) << 8) + 4 * g + (r >> 2);
        const float* src = W_hh + (size_t)row * Hh + 64 * s;
#pragma unroll
        for (int k = 0; k < CV_PAIRS; ++k)
            wv[r][k] = pkh2(src[2 * k], src[2 * k + 1]);
    }
    uint32_t wx[16][2];
#pragma unroll
    for (int r = 0; r < 16; ++r) {
        const int row = ((r & 3) << 8) + 4 * g + (r >> 2);
        const float* src = W_ih + (size_t)row * (Ff + 1) + 4 * s;
        wx[r][0] = pkh2(src[0], src[1]);
        wx[r][1] = pkh2(src[2], src[3]);
    }
    float bias[4];
#pragma unroll
    for (int G = 0; G < 4; ++G)
        bias[G] = b_ih[(G << 8) + tid] + b_hh[(G << 8) + tid];   // unit = tid
    const float wout = W_out[tid];
    const float bo   = b_out[0];

    // ---- stage LDS overflow weights: chunk c = (pc=c>>2, rg=c&3);
    // data = {pair(W_hh[256G+4g+rg][64s+2(CV+pc)]) : G=0..3} at [c][wave][lane]
#pragma unroll 1
    for (int c = 0; c < NCHUNK; ++c) {
        const int pc = c >> 2, rg = c & 3;
        const int col = 64 * s + 2 * (CV_PAIRS + pc);
        uint32_t d[4];
#pragma unroll
        for (int G = 0; G < 4; ++G) {
            const int row = (G << 8) + 4 * g + rg;
            const float* p = W_hh + (size_t)row * Hh + col;
            d[G] = pkh2(p[0], p[1]);
        }
        *reinterpret_cast<uint4*>(&lds_w[(uint32_t)c * 1024u + wbase]) =
            *reinterpret_cast<const uint4*>(d);
    }

    // ---- misc LDS init
    if (tid < 128) { abits[tid] = anomw[tid]; hbuf_u[tid] = 0u; }  // h0 = 0
    if (tid < 100) {
        const int cc = tid / 10 + 1, r = tid % 10;
        float S = 0.f;
        for (int i = 0; i < cc; ++i) S += __expf((float)i);
        const int shift = 10 - cc;
        w2[cc][r] = (r >= shift) ? __expf((float)(r - shift)) / S : 0.f;
    }

    float c_reg = 0.f, h_last = 0.f;
    float buf[10];
#pragma unroll
    for (int i = 0; i < 10; ++i) buf[i] = 0.f;
    int count = 1;

    __syncthreads();

    unsigned short* hs = reinterpret_cast<unsigned short*>(hbuf_u);

#pragma unroll 1
    for (int tc = 0; tc < Tt / 64; ++tc) {
        // stage x chunk: step ts, quarter q -> pairs 2q,2q+1 (features 4q..4q+3)
        {
            const int ts = tc * 64 + (tid >> 2), q = tid & 3;
            const float4 xv = *reinterpret_cast<const float4*>(
                &x[((size_t)b * Tt + ts) * Ff + q * 4]);
            xst[(tid >> 2) * 8 + q * 2]     = pkh2(xv.x, xv.y);
            xst[(tid >> 2) * 8 + q * 2 + 1] = pkh2(xv.z, xv.w);
        }
        __syncthreads();

#pragma unroll 1
        for (int tt = 0; tt < 64; ++tt) {
            const int t = tc * 64 + tt;
            const uint32_t* hb = hbuf_u + (t & 1) * 128 + s * 32;

            float acc[16];
#pragma unroll
            for (int r = 0; r < 16; ++r) acc[r] = 0.f;

            // phase A: VGPR-resident weights
#pragma unroll
            for (int k = 0; k < CV_PAIRS; ++k) {
                const uint32_t hk = hb[k];
#pragma unroll
                for (int r = 0; r < 16; ++r)
                    acc[r] = dot2f(wv[r][k], hk, acc[r]);
            }
            // phase B: LDS-resident weights (conflict-free b128 per chunk)
#pragma unroll
            for (int pc = 0; pc < LDS_PAIRS; ++pc) {
                const uint32_t hpp = hb[CV_PAIRS + pc];
#pragma unroll
                for (int rg = 0; rg < 4; ++rg) {
                    const int c = pc * 4 + rg;
                    const uint32_t* wc = &lds_w[(uint32_t)c * 1024u + wbase];
#pragma unroll
                    for (int G = 0; G < 4; ++G)
                        acc[rg * 4 + G] = dot2f(wc[G], hpp, acc[rg * 4 + G]);
                }
            }
            // phase X: input part (slice s owns features 4s..4s+3)
            {
                const uint32_t xp0 = xst[tt * 8 + s * 2];
                const uint32_t xp1 = xst[tt * 8 + s * 2 + 1];
#pragma unroll
                for (int r = 0; r < 16; ++r) {
                    acc[r] = dot2f(wx[r][0], xp0, acc[r]);
                    acc[r] = dot2f(wx[r][1], xp1, acc[r]);
                }
            }
            // butterfly over the 4 k-slices (lane bits 0-1)
#pragma unroll
            for (int r = 0; r < 16; ++r) acc[r] += __shfl_xor(acc[r], 1, 64);
#pragma unroll
            for (int r = 0; r < 16; ++r) acc[r] += __shfl_xor(acc[r], 2, 64);

            // static pick of this lane's unit (u == s): gate[G] = acc[s*4+G]
            float gate[4];
#pragma unroll
            for (int G = 0; G < 4; ++G) {
                const float t01 = (s & 1) ? acc[4 + G]  : acc[G];
                const float t23 = (s & 1) ? acc[12 + G] : acc[8 + G];
                gate[G] = ((s & 2) ? t23 : t01) + bias[G];
            }

            const float ig = sigm_(gate[0]);
            const float fg = sigm_(gate[1]);
            const float gg = tanh_(gate[2]);
            const float og = sigm_(gate[3]);
            const float new_c = fg * c_reg + ig * gg;
            const float new_h = og * tanh_(new_c);

            const uint32_t an = (abits[t >> 5] >> (t & 31)) & 1u;
            if (an) {
                // weighted = sum_i wts[i]*buf_logical[i]; reg r holds logical r-(10-count)
                float wsum = 0.f;
                const float* wt = w2[count];
#pragma unroll
                for (int i = 0; i < 10; ++i) wsum = fmaf(wt[i], buf[i], wsum);
                const float blend = wsum * (1.0f - MEM_DECAY) + new_c * MEM_DECAY;
                c_reg = c_reg * (1.0f - SMOOTH) + blend * SMOOTH;
                // buffer & count unchanged
            } else {
                c_reg = new_c;
#pragma unroll
                for (int i = 0; i < 9; ++i) buf[i] = buf[i + 1];
                buf[9] = new_c;
                count = min(count + 1, 10);
            }
            h_last = new_h;

            // publish h (f16) for next step
            {
                __half hv = __float2half_rn(new_h);
                hs[((t + 1) & 1) * 256 + tid] = __builtin_bit_cast(unsigned short, hv);
            }
            // output: out[b][t] = dot(W_out, h_next) + b_out
            float ov = new_h * wout;
#pragma unroll
            for (int m = 1; m < 64; m <<= 1) ov += __shfl_xor(ov, m, 64);
            if ((tid & 63) == 0) outp[t & 1][tid >> 6] = ov;

            __syncthreads();

            if (tid == 0)
                out[(size_t)b * Tt + t] =
                    outp[t & 1][0] + outp[t & 1][1] + outp[t & 1][2] + outp[t & 1][3] + bo;
        }
    }

    // final h, c (f32 from registers)
    out[(size_t)Bb * Tt + (size_t)b * Hh + tid] = h_last;
    out[(size_t)Bb * Tt + (size_t)Bb * Hh + (size_t)b * Hh + tid] = c_reg;
}

extern "C" void kernel_launch(void* const* d_in, const int* in_sizes, int n_in,
                              void* d_out, int out_size, void* d_ws, size_t ws_size,
                              hipStream_t stream) {
    (void)in_sizes; (void)n_in; (void)out_size;
    const float* x     = (const float*)d_in[0];
    const float* W_ih  = (const float*)d_in[1];
    const float* b_ih  = (const float*)d_in[2];
    const float* W_hh  = (const float*)d_in[3];
    const float* b_hh  = (const float*)d_in[4];
    const float* W_out = (const float*)d_in[5];
    const float* b_out = (const float*)d_in[6];
    float* out = (float*)d_out;

    // 128 u32 words of packed anomaly bits; prefer d_ws, fall back to the h-region
    // of d_out (overwritten by the epilogue) if ws is too small.
    uint32_t* anomw = (ws_size >= 512) ? (uint32_t*)d_ws
                                       : (uint32_t*)(out + (size_t)Bb * Tt);

    anom_kernel<<<64, 256, 0, stream>>>(x, anomw);
    lstm_kernel<<<Bb, 256, 0, stream>>>(x, W_ih, b_ih, W_hh, b_hh, W_out, b_out,
                                        anomw, out);
}

// Round 2
// 15286.707 us; speedup vs baseline: 1.0515x; 1.0515x over previous
//
#include <hip/hip_runtime.h>
#include <hip/hip_fp16.h>

// AlternatingForecastModel: 4096-step LSTM (B=256,H=256) with anomaly memory blend.
// 1 batch per CU (256 blocks x 256 threads, 1 wave/SIMD). W_hh f16 pairs per thread:
//   7 pairs/row in VGPR (112 regs) + 16 pairs/row in AGPR (256 regs, explicit
//   v_accvgpr_write/read asm) + 9 pairs/row in LDS (144KB, [chunk][wave][lane]
//   layout -> conflict-free ds_read_b128).
// k-split: lane s=tid&3 owns h-cols [64s,64s+64); 2-step shfl_xor butterfly.
// h double-buffer in LDS padded to stride 36 dwords (bank-conflict-free, b128-aligned).
// c and the W=10 memory buffer live in registers (shift-append + count-indexed table).
// Anomaly flags (batch-global, input-only) precomputed as packed bits.

#define Bb 256
#define Tt 4096
#define Ff 16
#define Hh 256
#define PV 7                    // pairs/row in VGPR
#define PA 16                   // pairs/row in AGPR
#define PL 9                    // pairs/row in LDS
#define NCHUNK (4 * PL)         // 36 x 4KB chunks
#define MEM_DECAY 0.3f
#define SMOOTH 0.1f

typedef _Float16 h2v __attribute__((ext_vector_type(2)));

__device__ __forceinline__ uint32_t pkh2(float a, float b) {
    __half2 h = __floats2half2_rn(a, b);
    return __builtin_bit_cast(uint32_t, h);
}

__device__ __forceinline__ float dot2f(uint32_t a, uint32_t b, float c) {
#if __has_builtin(__builtin_amdgcn_fdot2)
    return __builtin_amdgcn_fdot2(__builtin_bit_cast(h2v, a),
                                  __builtin_bit_cast(h2v, b), c, false);
#else
    h2v x = __builtin_bit_cast(h2v, a), y = __builtin_bit_cast(h2v, b);
    return c + (float)x[0] * (float)y[0] + (float)x[1] * (float)y[1];
#endif
}

// AGPR residency: write once at init, read per use (dep operand pins the read
// inside the time loop so LICM can't hoist 256 reads into VGPRs).
#define AGWR(dst, val) asm("v_accvgpr_write_b32 %0, %1" : "=a"(dst) : "v"(val))
#define AGRD(dst, src, dep) \
    asm("v_accvgpr_read_b32 %0, %1" : "=v"(dst) : "a"(src), "v"(dep))

__device__ __forceinline__ float sigm_(float x) { return 1.0f / (1.0f + __expf(-x)); }
__device__ __forceinline__ float tanh_(float x) { return 1.0f - 2.0f / (__expf(2.0f * x) + 1.0f); }

// ---------------- pre-kernel: packed anomaly bits (128 u32 words) ----------------
__global__ void __launch_bounds__(256) anom_kernel(const float* __restrict__ x,
                                                   uint32_t* __restrict__ anomw) {
    __shared__ uint32_t part[4][64];
    const int k = blockIdx.x, j = threadIdx.x;
    const int tsub = j & 63, bg = j >> 6;
    const int t = k * 64 + tsub;
    uint32_t a = 0;
    for (int b = bg * 64; b < bg * 64 + 64; ++b)
        a |= (x[((size_t)b * Tt + t) * Ff + (Ff - 1)] != 0.0f) ? 1u : 0u;
    part[bg][tsub] = a;
    __syncthreads();
    if (j < 64) {
        uint32_t any = part[0][j] | part[1][j] | part[2][j] | part[3][j];
        unsigned long long m = __ballot(any != 0);
        if (j == 0) {
            anomw[2 * k]     = (uint32_t)(m & 0xffffffffull);
            anomw[2 * k + 1] = (uint32_t)(m >> 32);
        }
    }
}

// ---------------- main kernel ----------------
__global__ void __launch_bounds__(256, 1) lstm_kernel(
    const float* __restrict__ x,
    const float* __restrict__ W_ih, const float* __restrict__ b_ih,
    const float* __restrict__ W_hh, const float* __restrict__ b_hh,
    const float* __restrict__ W_out, const float* __restrict__ b_out,
    const uint32_t* __restrict__ anomw,
    float* __restrict__ out)
{
    __shared__ uint32_t lds_w[NCHUNK * 1024];   // 147456 B
    __shared__ uint32_t xst[64 * 8];            // 2048 B
    __shared__ uint32_t hbuf_u[2 * 144];        // 1152 B, stride 36/slice (pad)
    __shared__ uint32_t abits[128];             // 512 B
    __shared__ float    w2[11][10];             // softmax-weight table by count
    __shared__ float    outp[2][4];

    const int tid = threadIdx.x;
    const int b   = blockIdx.x;
    const int g   = tid >> 2, s = tid & 3;
    const uint32_t wbase = (uint32_t)((tid >> 6) * 256 + (tid & 63) * 4);

    // ---- AGPR weights: wa[r][k] = pair at col 64s + 2(PV+k), row=((r&3)<<8)+4g+(r>>2)
    uint32_t wa[16][PA];
#pragma unroll
    for (int r = 0; r < 16; ++r) {
        const int row = ((r & 3) << 8) + 4 * g + (r >> 2);
        const float* src = W_hh + (size_t)row * Hh + 64 * s + 2 * PV;
#pragma unroll
        for (int k = 0; k < PA; ++k) {
            uint32_t v = pkh2(src[2 * k], src[2 * k + 1]);
            AGWR(wa[r][k], v);
        }
    }

    // ---- VGPR weights (pairs 0..PV-1)
    uint32_t wv[16][PV];
#pragma unroll
    for (int r = 0; r < 16; ++r) {
        const int row = ((r & 3) << 8) + 4 * g + (r >> 2);
        const float* src = W_hh + (size_t)row * Hh + 64 * s;
#pragma unroll
        for (int k = 0; k < PV; ++k)
            wv[r][k] = pkh2(src[2 * k], src[2 * k + 1]);
    }
    uint32_t wx[16][2];
#pragma unroll
    for (int r = 0; r < 16; ++r) {
        const int row = ((r & 3) << 8) + 4 * g + (r >> 2);
        const float* src = W_ih + (size_t)row * (Ff + 1) + 4 * s;
        wx[r][0] = pkh2(src[0], src[1]);
        wx[r][1] = pkh2(src[2], src[3]);
    }
    float bias[4];
#pragma unroll
    for (int G = 0; G < 4; ++G)
        bias[G] = b_ih[(G << 8) + tid] + b_hh[(G << 8) + tid];
    const float wout = W_out[tid];
    const float bo   = b_out[0];

    // ---- LDS weights (pairs PV+PA .. 31): chunk c=(pc,rg), [c][wave][lane][4dw]
#pragma unroll 1
    for (int c = 0; c < NCHUNK; ++c) {
        const int pc = c >> 2, rg = c & 3;
        const int col = 64 * s + 2 * (PV + PA + pc);
        uint32_t d[4];
#pragma unroll
        for (int G = 0; G < 4; ++G) {
            const int row = (G << 8) + 4 * g + rg;
            const float* p = W_hh + (size_t)row * Hh + col;
            d[G] = pkh2(p[0], p[1]);
        }
        *reinterpret_cast<uint4*>(&lds_w[(uint32_t)c * 1024u + wbase]) =
            *reinterpret_cast<const uint4*>(d);
    }

    // ---- misc LDS init
    if (tid < 128) abits[tid] = anomw[tid];
    for (int i = tid; i < 288; i += 256) hbuf_u[i] = 0u;   // h0 = 0 (both buffers)
    if (tid < 100) {
        const int cc = tid / 10 + 1, r = tid % 10;
        float S = 0.f;
        for (int i = 0; i < cc; ++i) S += __expf((float)i);
        const int shift = 10 - cc;
        w2[cc][r] = (r >= shift) ? __expf((float)(r - shift)) / S : 0.f;
    }

    float c_reg = 0.f, h_last = 0.f;
    float buf[10];
#pragma unroll
    for (int i = 0; i < 10; ++i) buf[i] = 0.f;
    int count = 1;

    __syncthreads();

    unsigned short* hs = reinterpret_cast<unsigned short*>(hbuf_u);

#pragma unroll 1
    for (int tc = 0; tc < Tt / 64; ++tc) {
        {   // stage 64 steps of x as f16 pairs
            const int ts = tc * 64 + (tid >> 2), q = tid & 3;
            const float4 xv = *reinterpret_cast<const float4*>(
                &x[((size_t)b * Tt + ts) * Ff + q * 4]);
            xst[(tid >> 2) * 8 + q * 2]     = pkh2(xv.x, xv.y);
            xst[(tid >> 2) * 8 + q * 2 + 1] = pkh2(xv.z, xv.w);
        }
        __syncthreads();

#pragma unroll 1
        for (int tt = 0; tt < 64; ++tt) {
            const int t = tc * 64 + tt;

            // h pairs for this slice: 8x ds_read_b128, conflict-free (stride 36)
            const uint32_t* hb = hbuf_u + (t & 1) * 144 + s * 36;
            uint32_t hp[32];
#pragma unroll
            for (int j = 0; j < 8; ++j) {
                const uint4 hv = *reinterpret_cast<const uint4*>(hb + 4 * j);
                hp[4 * j]     = hv.x;
                hp[4 * j + 1] = hv.y;
                hp[4 * j + 2] = hv.z;
                hp[4 * j + 3] = hv.w;
            }

            float acc[16];
#pragma unroll
            for (int r = 0; r < 16; ++r) acc[r] = 0.f;

            // phase B: LDS weights (issue loads early; overlaps VALU below)
#pragma unroll
            for (int pc = 0; pc < PL; ++pc) {
                const uint32_t hk = hp[PV + PA + pc];
#pragma unroll
                for (int rg = 0; rg < 4; ++rg) {
                    const uint4 wc = *reinterpret_cast<const uint4*>(
                        &lds_w[(uint32_t)(pc * 4 + rg) * 1024u + wbase]);
                    acc[rg * 4 + 0] = dot2f(wc.x, hk, acc[rg * 4 + 0]);
                    acc[rg * 4 + 1] = dot2f(wc.y, hk, acc[rg * 4 + 1]);
                    acc[rg * 4 + 2] = dot2f(wc.z, hk, acc[rg * 4 + 2]);
                    acc[rg * 4 + 3] = dot2f(wc.w, hk, acc[rg * 4 + 3]);
                }
            }
            // phase A: VGPR weights
#pragma unroll
            for (int k = 0; k < PV; ++k) {
                const uint32_t hk = hp[k];
#pragma unroll
                for (int r = 0; r < 16; ++r)
                    acc[r] = dot2f(wv[r][k], hk, acc[r]);
            }
            // phase AG: AGPR weights (read + dot2)
#pragma unroll
            for (int k = 0; k < PA; ++k) {
                const uint32_t hk = hp[PV + k];
#pragma unroll
                for (int r = 0; r < 16; ++r) {
                    uint32_t tw;
                    AGRD(tw, wa[r][k], hk);
                    acc[r] = dot2f(tw, hk, acc[r]);
                }
            }
            // phase X: input part
            {
                const uint2 xv2 = *reinterpret_cast<const uint2*>(&xst[tt * 8 + s * 2]);
#pragma unroll
                for (int r = 0; r < 16; ++r) {
                    acc[r] = dot2f(wx[r][0], xv2.x, acc[r]);
                    acc[r] = dot2f(wx[r][1], xv2.y, acc[r]);
                }
            }
            // butterfly over 4 k-slices
#pragma unroll
            for (int r = 0; r < 16; ++r) acc[r] += __shfl_xor(acc[r], 1, 64);
#pragma unroll
            for (int r = 0; r < 16; ++r) acc[r] += __shfl_xor(acc[r], 2, 64);

            float gate[4];
#pragma unroll
            for (int G = 0; G < 4; ++G) {
                const float t01 = (s & 1) ? acc[4 + G]  : acc[G];
                const float t23 = (s & 1) ? acc[12 + G] : acc[8 + G];
                gate[G] = ((s & 2) ? t23 : t01) + bias[G];
            }

            const float ig = sigm_(gate[0]);
            const float fg = sigm_(gate[1]);
            const float gg = tanh_(gate[2]);
            const float og = sigm_(gate[3]);
            const float new_c = fg * c_reg + ig * gg;
            const float new_h = og * tanh_(new_c);

            const uint32_t an = (abits[t >> 5] >> (t & 31)) & 1u;
            if (an) {
                float wsum = 0.f;
                const float* wt = w2[count];
#pragma unroll
                for (int i = 0; i < 10; ++i) wsum = fmaf(wt[i], buf[i], wsum);
                const float blend = wsum * (1.0f - MEM_DECAY) + new_c * MEM_DECAY;
                c_reg = c_reg * (1.0f - SMOOTH) + blend * SMOOTH;
            } else {
                c_reg = new_c;
#pragma unroll
                for (int i = 0; i < 9; ++i) buf[i] = buf[i + 1];
                buf[9] = new_c;
                count = min(count + 1, 10);
            }
            h_last = new_h;

            {   // publish h (f16) for step t+1; 2B/lane consecutive -> conflict-free
                __half hv = __float2half_rn(new_h);
                hs[((t + 1) & 1) * 288 + (tid >> 6) * 72 + (tid & 63)] =
                    __builtin_bit_cast(unsigned short, hv);
            }
            float ov = new_h * wout;
#pragma unroll
            for (int m = 1; m < 64; m <<= 1) ov += __shfl_xor(ov, m, 64);
            if ((tid & 63) == 0) outp[t & 1][tid >> 6] = ov;

            __syncthreads();

            if (tid == 0)
                out[(size_t)b * Tt + t] =
                    outp[t & 1][0] + outp[t & 1][1] + outp[t & 1][2] + outp[t & 1][3] + bo;
        }
    }

    out[(size_t)Bb * Tt + (size_t)b * Hh + tid] = h_last;
    out[(size_t)Bb * Tt + (size_t)Bb * Hh + (size_t)b * Hh + tid] = c_reg;
}

extern "C" void kernel_launch(void* const* d_in, const int* in_sizes, int n_in,
                              void* d_out, int out_size, void* d_ws, size_t ws_size,
                              hipStream_t stream) {
    (void)in_sizes; (void)n_in; (void)out_size;
    const float* x     = (const float*)d_in[0];
    const float* W_ih  = (const float*)d_in[1];
    const float* b_ih  = (const float*)d_in[2];
    const float* W_hh  = (const float*)d_in[3];
    const float* b_hh  = (const float*)d_in[4];
    const float* W_out = (const float*)d_in[5];
    const float* b_out = (const float*)d_in[6];
    float* out = (float*)d_out;

    uint32_t* anomw = (ws_size >= 512) ? (uint32_t*)d_ws
                                       : (uint32_t*)(out + (size_t)Bb * Tt);

    anom_kernel<<<64, 256, 0, stream>>>(x, anomw);
    lstm_kernel<<<Bb, 256, 0, stream>>>(x, W_ih, b_ih, W_hh, b_hh, W_out, b_out,
                                        anomw, out);
}

// Round 4
// 10933.800 us; speedup vs baseline: 1.4701x; 1.3981x over previous
//
#include <hip/hip_runtime.h>
#include <hip/hip_fp16.h>

// AlternatingForecastModel: 4096-step LSTM (B=256,H=256) with anomaly memory blend.
// v4 = v2-proven primitives + 512-thread structure (2 waves/SIMD):
//   - thread owns 8 gate-rows (2 units u0,u0+1) x k-slice s of 64 h-cols
//   - 23 W_hh pairs/row in VGPR (184 regs) + 9 pairs/row in LDS (144KB,
//     [chunk][tid][4dw], contiguous 1KB/wave -> conflict-free b128)
//   - W_ih (2 pairs/row) in VGPR; butterfly via __shfl_xor (proven)
//   - h double-buffer in LDS padded to 36-dword slice stride (proven, conflict-free)
//   - W=10 ring in f32 regs, shift-append + count-indexed softmax table (proven)

#define Bb 256
#define Tt 4096
#define Ff 16
#define Hh 256
#define PV 23                    // W_hh pairs/row in VGPRs
#define NSL 9                    // W_hh pairs/row in LDS
#define MEM_DECAY 0.3f
#define SMOOTH 0.1f

typedef _Float16 h2v __attribute__((ext_vector_type(2)));

__device__ __forceinline__ uint32_t pkh2(float a, float b) {
    __half2 h = __floats2half2_rn(a, b);
    return __builtin_bit_cast(uint32_t, h);
}

__device__ __forceinline__ float dot2f(uint32_t a, uint32_t b, float c) {
#if __has_builtin(__builtin_amdgcn_fdot2)
    return __builtin_amdgcn_fdot2(__builtin_bit_cast(h2v, a),
                                  __builtin_bit_cast(h2v, b), c, false);
#else
    h2v x = __builtin_bit_cast(h2v, a), y = __builtin_bit_cast(h2v, b);
    return c + (float)x[0] * (float)y[0] + (float)x[1] * (float)y[1];
#endif
}

__device__ __forceinline__ float sigm_(float x) { return 1.0f / (1.0f + __expf(-x)); }
__device__ __forceinline__ float tanh_(float x) { return 1.0f - 2.0f / (__expf(2.0f * x) + 1.0f); }

// ---------------- pre-kernel: packed anomaly bits (128 u32 words) ----------------
__global__ void __launch_bounds__(256) anom_kernel(const float* __restrict__ x,
                                                   uint32_t* __restrict__ anomw) {
    __shared__ uint32_t part[4][64];
    const int k = blockIdx.x, j = threadIdx.x;
    const int tsub = j & 63, bg = j >> 6;
    const int t = k * 64 + tsub;
    uint32_t a = 0;
    for (int b = bg * 64; b < bg * 64 + 64; ++b)
        a |= (x[((size_t)b * Tt + t) * Ff + (Ff - 1)] != 0.0f) ? 1u : 0u;
    part[bg][tsub] = a;
    __syncthreads();
    if (j < 64) {
        uint32_t any = part[0][j] | part[1][j] | part[2][j] | part[3][j];
        unsigned long long m = __ballot(any != 0);
        if (j == 0) {
            anomw[2 * k]     = (uint32_t)(m & 0xffffffffull);
            anomw[2 * k + 1] = (uint32_t)(m >> 32);
        }
    }
}

// ---------------- main kernel ----------------
__global__ void __launch_bounds__(512, 2) lstm_kernel(
    const float* __restrict__ x,
    const float* __restrict__ W_ih, const float* __restrict__ b_ih,
    const float* __restrict__ W_hh, const float* __restrict__ b_hh,
    const float* __restrict__ W_out, const float* __restrict__ b_out,
    const uint32_t* __restrict__ anomw,
    float* __restrict__ out)
{
    __shared__ uint4    lds_w4[2 * NSL * 512];        // 147456 B
    __shared__ uint32_t xst[64 * 8];                  // 2048 B
    __shared__ uint32_t hbuf[2 * 144];                // 1152 B (h f16 pairs, stride 36/slice)
    __shared__ uint32_t abits[128];                   // 512 B
    __shared__ float    w2[11][10];                   // softmax table by count
    __shared__ float    outp[2][8];

    const int tid = threadIdx.x;          // 0..511
    const int b   = blockIdx.x;
    const int s   = tid & 3;              // k-slice
    const int g   = tid >> 2;             // 0..127 -> units {2g, 2g+1}
    const int u0  = 2 * g;
    const int myu = u0 + (s & 1);         // own unit (lanes s and s+2 duplicate)

    // ---- VGPR W_hh: wv[r][k], r = u01*4+G, row = G*256 + u0 + u01, cols 64s+2k..+1
    uint32_t wv[8][PV];
#pragma unroll
    for (int r = 0; r < 8; ++r) {
        const int row = ((r & 3) << 8) + u0 + (r >> 2);
        const float* src = W_hh + (size_t)row * Hh + 64 * s;
#pragma unroll
        for (int k = 0; k < PV; ++k) {
            const float2 w2v = *reinterpret_cast<const float2*>(src + 2 * k);
            wv[r][k] = pkh2(w2v.x, w2v.y);
        }
    }
    // ---- VGPR W_ih: slice s owns features 4s..4s+3 (2 pairs)
    uint32_t wx[8][2];
#pragma unroll
    for (int r = 0; r < 8; ++r) {
        const int row = ((r & 3) << 8) + u0 + (r >> 2);
        const float* src = W_ih + (size_t)row * (Ff + 1) + 4 * s;
        wx[r][0] = pkh2(src[0], src[1]);
        wx[r][1] = pkh2(src[2], src[3]);
    }
    float bias[4];
#pragma unroll
    for (int G = 0; G < 4; ++G)
        bias[G] = b_ih[(G << 8) + myu] + b_hh[(G << 8) + myu];
    const float wout = W_out[myu];
    const float bo   = b_out[0];

    // ---- LDS W_hh pairs PV..PV+NSL-1: chunk c = j*2+u01, [c][tid][4dw]
#pragma unroll 1
    for (int c = 0; c < 2 * NSL; ++c) {
        const int j = c >> 1, u01 = c & 1;
        const int col = 64 * s + 2 * (PV + j);
        uint32_t d[4];
#pragma unroll
        for (int G = 0; G < 4; ++G) {
            const int row = (G << 8) + u0 + u01;
            const float2 w2v = *reinterpret_cast<const float2*>(
                W_hh + (size_t)row * Hh + col);
            d[G] = pkh2(w2v.x, w2v.y);
        }
        lds_w4[c * 512 + tid] = make_uint4(d[0], d[1], d[2], d[3]);
    }

    // ---- misc LDS init
    if (tid < 128) abits[tid] = anomw[tid];
    for (int i = tid; i < 288; i += 512) hbuf[i] = 0u;    // h0 = 0 (both phases)
    if (tid < 100) {
        const int cc = tid / 10 + 1, r = tid % 10;
        float S = 0.f;
        for (int i = 0; i < cc; ++i) S += __expf((float)i);
        const int shift = 10 - cc;
        w2[cc][r] = (r >= shift) ? __expf((float)(r - shift)) / S : 0.f;
    }

    float c_reg = 0.f, h_last = 0.f;
    float buf[10];
#pragma unroll
    for (int i = 0; i < 10; ++i) buf[i] = 0.f;
    int count = 1;

    __syncthreads();

    unsigned short* hs = reinterpret_cast<unsigned short*>(hbuf);

#pragma unroll 1
    for (int tc = 0; tc < Tt / 64; ++tc) {
        {   // stage 64 steps of x as f16 pairs (1 float2 per thread)
            const int ts = tc * 64 + (tid >> 3), q = tid & 7;
            const float2 xv = *reinterpret_cast<const float2*>(
                &x[((size_t)b * Tt + ts) * Ff + 2 * q]);
            xst[(tid >> 3) * 8 + q] = pkh2(xv.x, xv.y);
        }
        __syncthreads();

#pragma unroll 1
        for (int tt = 0; tt < 64; ++tt) {
            const int t = tc * 64 + tt;

            // h pairs for this slice: 8x b128, stride-36 padded -> conflict-free
            const uint32_t* hb = hbuf + (t & 1) * 144 + s * 36;
            uint32_t hp[32];
#pragma unroll
            for (int jj = 0; jj < 8; ++jj) {
                const uint4 hv = *reinterpret_cast<const uint4*>(hb + 4 * jj);
                hp[4 * jj]     = hv.x;
                hp[4 * jj + 1] = hv.y;
                hp[4 * jj + 2] = hv.z;
                hp[4 * jj + 3] = hv.w;
            }

            float acc[8];
#pragma unroll
            for (int r = 0; r < 8; ++r) acc[r] = 0.f;

            // LDS W_hh slots (contiguous 1KB/wave reads)
#pragma unroll
            for (int j = 0; j < NSL; ++j) {
                const uint32_t hk = hp[PV + j];
#pragma unroll
                for (int u01 = 0; u01 < 2; ++u01) {
                    const uint4 wc = lds_w4[(j * 2 + u01) * 512 + tid];
                    acc[u01 * 4 + 0] = dot2f(wc.x, hk, acc[u01 * 4 + 0]);
                    acc[u01 * 4 + 1] = dot2f(wc.y, hk, acc[u01 * 4 + 1]);
                    acc[u01 * 4 + 2] = dot2f(wc.z, hk, acc[u01 * 4 + 2]);
                    acc[u01 * 4 + 3] = dot2f(wc.w, hk, acc[u01 * 4 + 3]);
                }
            }
            // VGPR W_hh
#pragma unroll
            for (int k = 0; k < PV; ++k) {
                const uint32_t hk = hp[k];
#pragma unroll
                for (int r = 0; r < 8; ++r)
                    acc[r] = dot2f(wv[r][k], hk, acc[r]);
            }
            // input part
            {
                const uint32_t xp0 = xst[tt * 8 + 2 * s];
                const uint32_t xp1 = xst[tt * 8 + 2 * s + 1];
#pragma unroll
                for (int r = 0; r < 8; ++r) {
                    acc[r] = dot2f(wx[r][0], xp0, acc[r]);
                    acc[r] = dot2f(wx[r][1], xp1, acc[r]);
                }
            }
            // butterfly across the 4 k-slices (proven shfl_xor)
#pragma unroll
            for (int r = 0; r < 8; ++r) acc[r] += __shfl_xor(acc[r], 1, 64);
#pragma unroll
            for (int r = 0; r < 8; ++r) acc[r] += __shfl_xor(acc[r], 2, 64);

            float gate[4];
#pragma unroll
            for (int G = 0; G < 4; ++G)
                gate[G] = ((s & 1) ? acc[4 + G] : acc[G]) + bias[G];

            const float ig = sigm_(gate[0]);
            const float fg = sigm_(gate[1]);
            const float gg = tanh_(gate[2]);
            const float og = sigm_(gate[3]);
            const float new_c = fg * c_reg + ig * gg;
            const float new_h = og * tanh_(new_c);

            const uint32_t an = (abits[t >> 5] >> (t & 31)) & 1u;
            if (an) {
                float wsum = 0.f;
                const float* wt = w2[count];
#pragma unroll
                for (int i = 0; i < 10; ++i) wsum = fmaf(wt[i], buf[i], wsum);
                const float blend = wsum * (1.0f - MEM_DECAY) + new_c * MEM_DECAY;
                c_reg = c_reg * (1.0f - SMOOTH) + blend * SMOOTH;
            } else {
                c_reg = new_c;
#pragma unroll
                for (int i = 0; i < 9; ++i) buf[i] = buf[i + 1];
                buf[9] = new_c;
                count = min(count + 1, 10);
            }
            h_last = new_h;

            // publish h (f16) for step t+1, padded layout (unit u -> ushort 72*(u>>6)+(u&63))
            if (s < 2) {
                __half hv = __float2half_rn(new_h);
                hs[((t + 1) & 1) * 288 + (myu >> 6) * 72 + (myu & 63)] =
                    __builtin_bit_cast(unsigned short, hv);
            }
            // out[b][t]: per-wave shfl reduce (units counted once via s<2 mask)
            float ov = (s < 2) ? new_h * wout : 0.f;
#pragma unroll
            for (int m = 1; m < 64; m <<= 1) ov += __shfl_xor(ov, m, 64);
            if ((tid & 63) == 0) outp[t & 1][tid >> 6] = ov;

            __syncthreads();

            if (tid == 0) {
                float o = bo;
#pragma unroll
                for (int w = 0; w < 8; ++w) o += outp[t & 1][w];
                out[(size_t)b * Tt + t] = o;
            }
        }
    }

    // final h, c (f32 from registers)
    if (s < 2) {
        out[(size_t)Bb * Tt + (size_t)b * Hh + myu] = h_last;
        out[(size_t)Bb * Tt + (size_t)Bb * Hh + (size_t)b * Hh + myu] = c_reg;
    }
}

extern "C" void kernel_launch(void* const* d_in, const int* in_sizes, int n_in,
                              void* d_out, int out_size, void* d_ws, size_t ws_size,
                              hipStream_t stream) {
    (void)in_sizes; (void)n_in; (void)out_size;
    const float* x     = (const float*)d_in[0];
    const float* W_ih  = (const float*)d_in[1];
    const float* b_ih  = (const float*)d_in[2];
    const float* W_hh  = (const float*)d_in[3];
    const float* b_hh  = (const float*)d_in[4];
    const float* W_out = (const float*)d_in[5];
    const float* b_out = (const float*)d_in[6];
    float* out = (float*)d_out;

    uint32_t* anomw = (ws_size >= 512) ? (uint32_t*)d_ws
                                       : (uint32_t*)(out + (size_t)Bb * Tt);

    anom_kernel<<<64, 256, 0, stream>>>(x, anomw);
    lstm_kernel<<<Bb, 512, 0, stream>>>(x, W_ih, b_ih, W_hh, b_hh, W_out, b_out,
                                        anomw, out);
}

// Round 5
// 10921.175 us; speedup vs baseline: 1.4718x; 1.0012x over previous
//
#include <hip/hip_runtime.h>
#include <hip/hip_fp16.h>

// AlternatingForecastModel: 4096-step LSTM (B=256,H=256) with anomaly memory blend.
// v5 = v4 with the spill fixed:
//   - __launch_bounds__(512) (no 2nd arg): hipcc treats 2nd arg as WG/CU -> v4's
//     (512,2) capped VGPR at 128 and spilled ~130 regs (WRITE_SIZE 103MB).
//     Bare 512 -> cap 256 (2 waves/SIMD launchability), still 2-wave hiding.
//   - h-pair loads phased (A: 23..31, B1: 0..11, B2: 12..22) with sched_barrier(0)
//     fences to keep peak live regs ~250 < 256.
//   - all other primitives identical to v4 (proven passing).

#define Bb 256
#define Tt 4096
#define Ff 16
#define Hh 256
#define PV 23                    // W_hh pairs/row in VGPRs (pairs 0..22)
#define NSL 9                    // W_hh pairs/row in LDS  (pairs 23..31)
#define MEM_DECAY 0.3f
#define SMOOTH 0.1f

typedef _Float16 h2v __attribute__((ext_vector_type(2)));

__device__ __forceinline__ uint32_t pkh2(float a, float b) {
    __half2 h = __floats2half2_rn(a, b);
    return __builtin_bit_cast(uint32_t, h);
}

__device__ __forceinline__ float dot2f(uint32_t a, uint32_t b, float c) {
#if __has_builtin(__builtin_amdgcn_fdot2)
    return __builtin_amdgcn_fdot2(__builtin_bit_cast(h2v, a),
                                  __builtin_bit_cast(h2v, b), c, false);
#else
    h2v x = __builtin_bit_cast(h2v, a), y = __builtin_bit_cast(h2v, b);
    return c + (float)x[0] * (float)y[0] + (float)x[1] * (float)y[1];
#endif
}

__device__ __forceinline__ float sigm_(float x) { return 1.0f / (1.0f + __expf(-x)); }
__device__ __forceinline__ float tanh_(float x) { return 1.0f - 2.0f / (__expf(2.0f * x) + 1.0f); }

// ---------------- pre-kernel: packed anomaly bits (128 u32 words) ----------------
__global__ void __launch_bounds__(256) anom_kernel(const float* __restrict__ x,
                                                   uint32_t* __restrict__ anomw) {
    __shared__ uint32_t part[4][64];
    const int k = blockIdx.x, j = threadIdx.x;
    const int tsub = j & 63, bg = j >> 6;
    const int t = k * 64 + tsub;
    uint32_t a = 0;
    for (int b = bg * 64; b < bg * 64 + 64; ++b)
        a |= (x[((size_t)b * Tt + t) * Ff + (Ff - 1)] != 0.0f) ? 1u : 0u;
    part[bg][tsub] = a;
    __syncthreads();
    if (j < 64) {
        uint32_t any = part[0][j] | part[1][j] | part[2][j] | part[3][j];
        unsigned long long m = __ballot(any != 0);
        if (j == 0) {
            anomw[2 * k]     = (uint32_t)(m & 0xffffffffull);
            anomw[2 * k + 1] = (uint32_t)(m >> 32);
        }
    }
}

// ---------------- main kernel ----------------
__global__ void __launch_bounds__(512) lstm_kernel(
    const float* __restrict__ x,
    const float* __restrict__ W_ih, const float* __restrict__ b_ih,
    const float* __restrict__ W_hh, const float* __restrict__ b_hh,
    const float* __restrict__ W_out, const float* __restrict__ b_out,
    const uint32_t* __restrict__ anomw,
    float* __restrict__ out)
{
    __shared__ uint4    lds_w4[2 * NSL * 512];        // 147456 B
    __shared__ uint32_t xst[64 * 8];                  // 2048 B
    __shared__ uint32_t hbuf[2 * 144];                // 1152 B (h f16 pairs, stride 36/slice)
    __shared__ uint32_t abits[128];                   // 512 B
    __shared__ float    w2[11][10];                   // softmax table by count
    __shared__ float    outp[2][8];

    const int tid = threadIdx.x;          // 0..511
    const int b   = blockIdx.x;
    const int s   = tid & 3;              // k-slice
    const int g   = tid >> 2;             // 0..127 -> units {2g, 2g+1}
    const int u0  = 2 * g;
    const int myu = u0 + (s & 1);         // own unit (lanes s and s+2 duplicate)

    // ---- VGPR W_hh: wv[r][k], r = u01*4+G, row = G*256 + u0 + u01, cols 64s+2k..+1
    uint32_t wv[8][PV];
#pragma unroll
    for (int r = 0; r < 8; ++r) {
        const int row = ((r & 3) << 8) + u0 + (r >> 2);
        const float* src = W_hh + (size_t)row * Hh + 64 * s;
#pragma unroll
        for (int k = 0; k < PV; ++k) {
            const float2 w2v = *reinterpret_cast<const float2*>(src + 2 * k);
            wv[r][k] = pkh2(w2v.x, w2v.y);
        }
    }
    // ---- VGPR W_ih: slice s owns features 4s..4s+3 (2 pairs)
    uint32_t wx[8][2];
#pragma unroll
    for (int r = 0; r < 8; ++r) {
        const int row = ((r & 3) << 8) + u0 + (r >> 2);
        const float* src = W_ih + (size_t)row * (Ff + 1) + 4 * s;
        wx[r][0] = pkh2(src[0], src[1]);
        wx[r][1] = pkh2(src[2], src[3]);
    }
    float bias[4];
#pragma unroll
    for (int G = 0; G < 4; ++G)
        bias[G] = b_ih[(G << 8) + myu] + b_hh[(G << 8) + myu];
    const float wout = W_out[myu];
    const float bo   = b_out[0];

    // ---- LDS W_hh pairs PV..PV+NSL-1: chunk c = j*2+u01, [c][tid][4dw]
#pragma unroll 1
    for (int c = 0; c < 2 * NSL; ++c) {
        const int j = c >> 1, u01 = c & 1;
        const int col = 64 * s + 2 * (PV + j);
        uint32_t d[4];
#pragma unroll
        for (int G = 0; G < 4; ++G) {
            const int row = (G << 8) + u0 + u01;
            const float2 w2v = *reinterpret_cast<const float2*>(
                W_hh + (size_t)row * Hh + col);
            d[G] = pkh2(w2v.x, w2v.y);
        }
        lds_w4[c * 512 + tid] = make_uint4(d[0], d[1], d[2], d[3]);
    }

    // ---- misc LDS init
    if (tid < 128) abits[tid] = anomw[tid];
    for (int i = tid; i < 288; i += 512) hbuf[i] = 0u;    // h0 = 0 (both phases)
    if (tid < 100) {
        const int cc = tid / 10 + 1, r = tid % 10;
        float S = 0.f;
        for (int i = 0; i < cc; ++i) S += __expf((float)i);
        const int shift = 10 - cc;
        w2[cc][r] = (r >= shift) ? __expf((float)(r - shift)) / S : 0.f;
    }

    float c_reg = 0.f, h_last = 0.f;
    float buf[10];
#pragma unroll
    for (int i = 0; i < 10; ++i) buf[i] = 0.f;
    int count = 1;

    __syncthreads();

    unsigned short* hs = reinterpret_cast<unsigned short*>(hbuf);

#pragma unroll 1
    for (int tc = 0; tc < Tt / 64; ++tc) {
        {   // stage 64 steps of x as f16 pairs (1 float2 per thread)
            const int ts = tc * 64 + (tid >> 3), q = tid & 7;
            const float2 xv = *reinterpret_cast<const float2*>(
                &x[((size_t)b * Tt + ts) * Ff + 2 * q]);
            xst[(tid >> 3) * 8 + q] = pkh2(xv.x, xv.y);
        }
        __syncthreads();

#pragma unroll 1
        for (int tt = 0; tt < 64; ++tt) {
            const int t = tc * 64 + tt;
            const uint32_t* hb = hbuf + (t & 1) * 144 + s * 36;

            float acc[8];
#pragma unroll
            for (int r = 0; r < 8; ++r) acc[r] = 0.f;

            // ---- phase A: h pairs 23..31 + LDS-resident weight MACs
            {
                const uint32_t hA0 = hb[23];
                const uint4 hA1 = *reinterpret_cast<const uint4*>(hb + 24);
                const uint4 hA2 = *reinterpret_cast<const uint4*>(hb + 28);
                const uint32_t hkA[9] = {hA0, hA1.x, hA1.y, hA1.z, hA1.w,
                                              hA2.x, hA2.y, hA2.z, hA2.w};
#pragma unroll
                for (int j = 0; j < NSL; ++j) {
                    const uint32_t hk = hkA[j];
#pragma unroll
                    for (int u01 = 0; u01 < 2; ++u01) {
                        const uint4 wc = lds_w4[(j * 2 + u01) * 512 + tid];
                        acc[u01 * 4 + 0] = dot2f(wc.x, hk, acc[u01 * 4 + 0]);
                        acc[u01 * 4 + 1] = dot2f(wc.y, hk, acc[u01 * 4 + 1]);
                        acc[u01 * 4 + 2] = dot2f(wc.z, hk, acc[u01 * 4 + 2]);
                        acc[u01 * 4 + 3] = dot2f(wc.w, hk, acc[u01 * 4 + 3]);
                    }
                }
            }
            // ---- x part
            {
                const uint32_t xp0 = xst[tt * 8 + 2 * s];
                const uint32_t xp1 = xst[tt * 8 + 2 * s + 1];
#pragma unroll
                for (int r = 0; r < 8; ++r) {
                    acc[r] = dot2f(wx[r][0], xp0, acc[r]);
                    acc[r] = dot2f(wx[r][1], xp1, acc[r]);
                }
            }
            __builtin_amdgcn_sched_barrier(0);
            // ---- phase B1: h pairs 0..11 + VGPR weight MACs
            {
                const uint4 h0 = *reinterpret_cast<const uint4*>(hb + 0);
                const uint4 h1 = *reinterpret_cast<const uint4*>(hb + 4);
                const uint4 h2 = *reinterpret_cast<const uint4*>(hb + 8);
                const uint32_t hkB[12] = {h0.x, h0.y, h0.z, h0.w,
                                          h1.x, h1.y, h1.z, h1.w,
                                          h2.x, h2.y, h2.z, h2.w};
#pragma unroll
                for (int k = 0; k < 12; ++k) {
                    const uint32_t hk = hkB[k];
#pragma unroll
                    for (int r = 0; r < 8; ++r)
                        acc[r] = dot2f(wv[r][k], hk, acc[r]);
                }
            }
            __builtin_amdgcn_sched_barrier(0);
            // ---- phase B2: h pairs 12..22 + VGPR weight MACs
            {
                const uint4 h3 = *reinterpret_cast<const uint4*>(hb + 12);
                const uint4 h4 = *reinterpret_cast<const uint4*>(hb + 16);
                const uint32_t h20 = hb[20], h21 = hb[21], h22 = hb[22];
                const uint32_t hkC[11] = {h3.x, h3.y, h3.z, h3.w,
                                          h4.x, h4.y, h4.z, h4.w,
                                          h20, h21, h22};
#pragma unroll
                for (int k = 0; k < 11; ++k) {
                    const uint32_t hk = hkC[k];
#pragma unroll
                    for (int r = 0; r < 8; ++r)
                        acc[r] = dot2f(wv[r][12 + k], hk, acc[r]);
                }
            }

            // butterfly across the 4 k-slices
#pragma unroll
            for (int r = 0; r < 8; ++r) acc[r] += __shfl_xor(acc[r], 1, 64);
#pragma unroll
            for (int r = 0; r < 8; ++r) acc[r] += __shfl_xor(acc[r], 2, 64);

            float gate[4];
#pragma unroll
            for (int G = 0; G < 4; ++G)
                gate[G] = ((s & 1) ? acc[4 + G] : acc[G]) + bias[G];

            const float ig = sigm_(gate[0]);
            const float fg = sigm_(gate[1]);
            const float gg = tanh_(gate[2]);
            const float og = sigm_(gate[3]);
            const float new_c = fg * c_reg + ig * gg;
            const float new_h = og * tanh_(new_c);

            const uint32_t an = (abits[t >> 5] >> (t & 31)) & 1u;
            if (an) {
                float wsum = 0.f;
                const float* wt = w2[count];
#pragma unroll
                for (int i = 0; i < 10; ++i) wsum = fmaf(wt[i], buf[i], wsum);
                const float blend = wsum * (1.0f - MEM_DECAY) + new_c * MEM_DECAY;
                c_reg = c_reg * (1.0f - SMOOTH) + blend * SMOOTH;
            } else {
                c_reg = new_c;
#pragma unroll
                for (int i = 0; i < 9; ++i) buf[i] = buf[i + 1];
                buf[9] = new_c;
                count = min(count + 1, 10);
            }
            h_last = new_h;

            // publish h (f16) for step t+1, padded layout
            if (s < 2) {
                __half hv = __float2half_rn(new_h);
                hs[((t + 1) & 1) * 288 + (myu >> 6) * 72 + (myu & 63)] =
                    __builtin_bit_cast(unsigned short, hv);
            }
            // out[b][t]: per-wave shfl reduce (units counted once via s<2 mask)
            float ov = (s < 2) ? new_h * wout : 0.f;
#pragma unroll
            for (int m = 1; m < 64; m <<= 1) ov += __shfl_xor(ov, m, 64);
            if ((tid & 63) == 0) outp[t & 1][tid >> 6] = ov;

            __syncthreads();

            if (tid == 0) {
                float o = bo;
#pragma unroll
                for (int w = 0; w < 8; ++w) o += outp[t & 1][w];
                out[(size_t)b * Tt + t] = o;
            }
        }
    }

    // final h, c (f32 from registers)
    if (s < 2) {
        out[(size_t)Bb * Tt + (size_t)b * Hh + myu] = h_last;
        out[(size_t)Bb * Tt + (size_t)Bb * Hh + (size_t)b * Hh + myu] = c_reg;
    }
}

extern "C" void kernel_launch(void* const* d_in, const int* in_sizes, int n_in,
                              void* d_out, int out_size, void* d_ws, size_t ws_size,
                              hipStream_t stream) {
    (void)in_sizes; (void)n_in; (void)out_size;
    const float* x     = (const float*)d_in[0];
    const float* W_ih  = (const float*)d_in[1];
    const float* b_ih  = (const float*)d_in[2];
    const float* W_hh  = (const float*)d_in[3];
    const float* b_hh  = (const float*)d_in[4];
    const float* W_out = (const float*)d_in[5];
    const float* b_out = (const float*)d_in[6];
    float* out = (float*)d_out;

    uint32_t* anomw = (ws_size >= 512) ? (uint32_t*)d_ws
                                       : (uint32_t*)(out + (size_t)Bb * Tt);

    anom_kernel<<<64, 256, 0, stream>>>(x, anomw);
    lstm_kernel<<<Bb, 512, 0, stream>>>(x, W_ih, b_ih, W_hh, b_hh, W_out, b_out,
                                        anomw, out);
}

// Round 6
// 10912.463 us; speedup vs baseline: 1.4730x; 1.0008x over previous
//
#include <hip/hip_runtime.h>
#include <hip/hip_fp16.h>

// AlternatingForecastModel: 4096-step LSTM (B=256,H=256) with anomaly memory blend.
// v6 = v5 with the register cap actually fixed:
//   - __launch_bounds__(512, 1): min 1 wave/EU -> 256-VGPR cap. Evidence:
//     (256,1) gave VGPR=256 (r1/r2); (512,2) and bare (512) both gave VGPR=128
//     (backend occupancy heuristic) -> ~130 spilled regs -> WRITE_SIZE ~100MB.
//     LDS (148KB) limits to 1 block/CU = 2 waves/SIMD = exactly the 512-reg pool.
//   - everything else identical to v5 (proven passing, conflicts = 0).

#define Bb 256
#define Tt 4096
#define Ff 16
#define Hh 256
#define PV 23                    // W_hh pairs/row in VGPRs (pairs 0..22)
#define NSL 9                    // W_hh pairs/row in LDS  (pairs 23..31)
#define MEM_DECAY 0.3f
#define SMOOTH 0.1f

typedef _Float16 h2v __attribute__((ext_vector_type(2)));

__device__ __forceinline__ uint32_t pkh2(float a, float b) {
    __half2 h = __floats2half2_rn(a, b);
    return __builtin_bit_cast(uint32_t, h);
}

__device__ __forceinline__ float dot2f(uint32_t a, uint32_t b, float c) {
#if __has_builtin(__builtin_amdgcn_fdot2)
    return __builtin_amdgcn_fdot2(__builtin_bit_cast(h2v, a),
                                  __builtin_bit_cast(h2v, b), c, false);
#else
    h2v x = __builtin_bit_cast(h2v, a), y = __builtin_bit_cast(h2v, b);
    return c + (float)x[0] * (float)y[0] + (float)x[1] * (float)y[1];
#endif
}

__device__ __forceinline__ float sigm_(float x) { return 1.0f / (1.0f + __expf(-x)); }
__device__ __forceinline__ float tanh_(float x) { return 1.0f - 2.0f / (__expf(2.0f * x) + 1.0f); }

// ---------------- pre-kernel: packed anomaly bits (128 u32 words) ----------------
__global__ void __launch_bounds__(256) anom_kernel(const float* __restrict__ x,
                                                   uint32_t* __restrict__ anomw) {
    __shared__ uint32_t part[4][64];
    const int k = blockIdx.x, j = threadIdx.x;
    const int tsub = j & 63, bg = j >> 6;
    const int t = k * 64 + tsub;
    uint32_t a = 0;
    for (int b = bg * 64; b < bg * 64 + 64; ++b)
        a |= (x[((size_t)b * Tt + t) * Ff + (Ff - 1)] != 0.0f) ? 1u : 0u;
    part[bg][tsub] = a;
    __syncthreads();
    if (j < 64) {
        uint32_t any = part[0][j] | part[1][j] | part[2][j] | part[3][j];
        unsigned long long m = __ballot(any != 0);
        if (j == 0) {
            anomw[2 * k]     = (uint32_t)(m & 0xffffffffull);
            anomw[2 * k + 1] = (uint32_t)(m >> 32);
        }
    }
}

// ---------------- main kernel ----------------
__global__ void __launch_bounds__(512, 1) lstm_kernel(
    const float* __restrict__ x,
    const float* __restrict__ W_ih, const float* __restrict__ b_ih,
    const float* __restrict__ W_hh, const float* __restrict__ b_hh,
    const float* __restrict__ W_out, const float* __restrict__ b_out,
    const uint32_t* __restrict__ anomw,
    float* __restrict__ out)
{
    __shared__ uint4    lds_w4[2 * NSL * 512];        // 147456 B
    __shared__ uint32_t xst[64 * 8];                  // 2048 B
    __shared__ uint32_t hbuf[2 * 144];                // 1152 B (h f16 pairs, stride 36/slice)
    __shared__ uint32_t abits[128];                   // 512 B
    __shared__ float    w2[11][10];                   // softmax table by count
    __shared__ float    outp[2][8];

    const int tid = threadIdx.x;          // 0..511
    const int b   = blockIdx.x;
    const int s   = tid & 3;              // k-slice
    const int g   = tid >> 2;             // 0..127 -> units {2g, 2g+1}
    const int u0  = 2 * g;
    const int myu = u0 + (s & 1);         // own unit (lanes s and s+2 duplicate)

    // ---- VGPR W_hh: wv[r][k], r = u01*4+G, row = G*256 + u0 + u01, cols 64s+2k..+1
    uint32_t wv[8][PV];
#pragma unroll
    for (int r = 0; r < 8; ++r) {
        const int row = ((r & 3) << 8) + u0 + (r >> 2);
        const float* src = W_hh + (size_t)row * Hh + 64 * s;
#pragma unroll
        for (int k = 0; k < PV; ++k) {
            const float2 w2v = *reinterpret_cast<const float2*>(src + 2 * k);
            wv[r][k] = pkh2(w2v.x, w2v.y);
        }
    }
    // ---- VGPR W_ih: slice s owns features 4s..4s+3 (2 pairs)
    uint32_t wx[8][2];
#pragma unroll
    for (int r = 0; r < 8; ++r) {
        const int row = ((r & 3) << 8) + u0 + (r >> 2);
        const float* src = W_ih + (size_t)row * (Ff + 1) + 4 * s;
        wx[r][0] = pkh2(src[0], src[1]);
        wx[r][1] = pkh2(src[2], src[3]);
    }
    float bias[4];
#pragma unroll
    for (int G = 0; G < 4; ++G)
        bias[G] = b_ih[(G << 8) + myu] + b_hh[(G << 8) + myu];
    const float wout = W_out[myu];
    const float bo   = b_out[0];

    // ---- LDS W_hh pairs PV..PV+NSL-1: chunk c = j*2+u01, [c][tid][4dw]
#pragma unroll 1
    for (int c = 0; c < 2 * NSL; ++c) {
        const int j = c >> 1, u01 = c & 1;
        const int col = 64 * s + 2 * (PV + j);
        uint32_t d[4];
#pragma unroll
        for (int G = 0; G < 4; ++G) {
            const int row = (G << 8) + u0 + u01;
            const float2 w2v = *reinterpret_cast<const float2*>(
                W_hh + (size_t)row * Hh + col);
            d[G] = pkh2(w2v.x, w2v.y);
        }
        lds_w4[c * 512 + tid] = make_uint4(d[0], d[1], d[2], d[3]);
    }

    // ---- misc LDS init
    if (tid < 128) abits[tid] = anomw[tid];
    for (int i = tid; i < 288; i += 512) hbuf[i] = 0u;    // h0 = 0 (both phases)
    if (tid < 100) {
        const int cc = tid / 10 + 1, r = tid % 10;
        float S = 0.f;
        for (int i = 0; i < cc; ++i) S += __expf((float)i);
        const int shift = 10 - cc;
        w2[cc][r] = (r >= shift) ? __expf((float)(r - shift)) / S : 0.f;
    }

    float c_reg = 0.f, h_last = 0.f;
    float buf[10];
#pragma unroll
    for (int i = 0; i < 10; ++i) buf[i] = 0.f;
    int count = 1;

    __syncthreads();

    unsigned short* hs = reinterpret_cast<unsigned short*>(hbuf);

#pragma unroll 1
    for (int tc = 0; tc < Tt / 64; ++tc) {
        {   // stage 64 steps of x as f16 pairs (1 float2 per thread)
            const int ts = tc * 64 + (tid >> 3), q = tid & 7;
            const float2 xv = *reinterpret_cast<const float2*>(
                &x[((size_t)b * Tt + ts) * Ff + 2 * q]);
            xst[(tid >> 3) * 8 + q] = pkh2(xv.x, xv.y);
        }
        __syncthreads();

#pragma unroll 1
        for (int tt = 0; tt < 64; ++tt) {
            const int t = tc * 64 + tt;
            const uint32_t* hb = hbuf + (t & 1) * 144 + s * 36;

            float acc[8];
#pragma unroll
            for (int r = 0; r < 8; ++r) acc[r] = 0.f;

            // ---- phase A: h pairs 23..31 + LDS-resident weight MACs
            {
                const uint32_t hA0 = hb[23];
                const uint4 hA1 = *reinterpret_cast<const uint4*>(hb + 24);
                const uint4 hA2 = *reinterpret_cast<const uint4*>(hb + 28);
                const uint32_t hkA[9] = {hA0, hA1.x, hA1.y, hA1.z, hA1.w,
                                              hA2.x, hA2.y, hA2.z, hA2.w};
#pragma unroll
                for (int j = 0; j < NSL; ++j) {
                    const uint32_t hk = hkA[j];
#pragma unroll
                    for (int u01 = 0; u01 < 2; ++u01) {
                        const uint4 wc = lds_w4[(j * 2 + u01) * 512 + tid];
                        acc[u01 * 4 + 0] = dot2f(wc.x, hk, acc[u01 * 4 + 0]);
                        acc[u01 * 4 + 1] = dot2f(wc.y, hk, acc[u01 * 4 + 1]);
                        acc[u01 * 4 + 2] = dot2f(wc.z, hk, acc[u01 * 4 + 2]);
                        acc[u01 * 4 + 3] = dot2f(wc.w, hk, acc[u01 * 4 + 3]);
                    }
                }
            }
            // ---- x part
            {
                const uint32_t xp0 = xst[tt * 8 + 2 * s];
                const uint32_t xp1 = xst[tt * 8 + 2 * s + 1];
#pragma unroll
                for (int r = 0; r < 8; ++r) {
                    acc[r] = dot2f(wx[r][0], xp0, acc[r]);
                    acc[r] = dot2f(wx[r][1], xp1, acc[r]);
                }
            }
            __builtin_amdgcn_sched_barrier(0);
            // ---- phase B1: h pairs 0..11 + VGPR weight MACs
            {
                const uint4 h0 = *reinterpret_cast<const uint4*>(hb + 0);
                const uint4 h1 = *reinterpret_cast<const uint4*>(hb + 4);
                const uint4 h2 = *reinterpret_cast<const uint4*>(hb + 8);
                const uint32_t hkB[12] = {h0.x, h0.y, h0.z, h0.w,
                                          h1.x, h1.y, h1.z, h1.w,
                                          h2.x, h2.y, h2.z, h2.w};
#pragma unroll
                for (int k = 0; k < 12; ++k) {
                    const uint32_t hk = hkB[k];
#pragma unroll
                    for (int r = 0; r < 8; ++r)
                        acc[r] = dot2f(wv[r][k], hk, acc[r]);
                }
            }
            __builtin_amdgcn_sched_barrier(0);
            // ---- phase B2: h pairs 12..22 + VGPR weight MACs
            {
                const uint4 h3 = *reinterpret_cast<const uint4*>(hb + 12);
                const uint4 h4 = *reinterpret_cast<const uint4*>(hb + 16);
                const uint32_t h20 = hb[20], h21 = hb[21], h22 = hb[22];
                const uint32_t hkC[11] = {h3.x, h3.y, h3.z, h3.w,
                                          h4.x, h4.y, h4.z, h4.w,
                                          h20, h21, h22};
#pragma unroll
                for (int k = 0; k < 11; ++k) {
                    const uint32_t hk = hkC[k];
#pragma unroll
                    for (int r = 0; r < 8; ++r)
                        acc[r] = dot2f(wv[r][12 + k], hk, acc[r]);
                }
            }

            // butterfly across the 4 k-slices
#pragma unroll
            for (int r = 0; r < 8; ++r) acc[r] += __shfl_xor(acc[r], 1, 64);
#pragma unroll
            for (int r = 0; r < 8; ++r) acc[r] += __shfl_xor(acc[r], 2, 64);

            float gate[4];
#pragma unroll
            for (int G = 0; G < 4; ++G)
                gate[G] = ((s & 1) ? acc[4 + G] : acc[G]) + bias[G];

            const float ig = sigm_(gate[0]);
            const float fg = sigm_(gate[1]);
            const float gg = tanh_(gate[2]);
            const float og = sigm_(gate[3]);
            const float new_c = fg * c_reg + ig * gg;
            const float new_h = og * tanh_(new_c);

            const uint32_t an = (abits[t >> 5] >> (t & 31)) & 1u;
            if (an) {
                float wsum = 0.f;
                const float* wt = w2[count];
#pragma unroll
                for (int i = 0; i < 10; ++i) wsum = fmaf(wt[i], buf[i], wsum);
                const float blend = wsum * (1.0f - MEM_DECAY) + new_c * MEM_DECAY;
                c_reg = c_reg * (1.0f - SMOOTH) + blend * SMOOTH;
            } else {
                c_reg = new_c;
#pragma unroll
                for (int i = 0; i < 9; ++i) buf[i] = buf[i + 1];
                buf[9] = new_c;
                count = min(count + 1, 10);
            }
            h_last = new_h;

            // publish h (f16) for step t+1, padded layout
            if (s < 2) {
                __half hv = __float2half_rn(new_h);
                hs[((t + 1) & 1) * 288 + (myu >> 6) * 72 + (myu & 63)] =
                    __builtin_bit_cast(unsigned short, hv);
            }
            // out[b][t]: per-wave shfl reduce (units counted once via s<2 mask)
            float ov = (s < 2) ? new_h * wout : 0.f;
#pragma unroll
            for (int m = 1; m < 64; m <<= 1) ov += __shfl_xor(ov, m, 64);
            if ((tid & 63) == 0) outp[t & 1][tid >> 6] = ov;

            __syncthreads();

            if (tid == 0) {
                float o = bo;
#pragma unroll
                for (int w = 0; w < 8; ++w) o += outp[t & 1][w];
                out[(size_t)b * Tt + t] = o;
            }
        }
    }

    // final h, c (f32 from registers)
    if (s < 2) {
        out[(size_t)Bb * Tt + (size_t)b * Hh + myu] = h_last;
        out[(size_t)Bb * Tt + (size_t)Bb * Hh + (size_t)b * Hh + myu] = c_reg;
    }
}

extern "C" void kernel_launch(void* const* d_in, const int* in_sizes, int n_in,
                              void* d_out, int out_size, void* d_ws, size_t ws_size,
                              hipStream_t stream) {
    (void)in_sizes; (void)n_in; (void)out_size;
    const float* x     = (const float*)d_in[0];
    const float* W_ih  = (const float*)d_in[1];
    const float* b_ih  = (const float*)d_in[2];
    const float* W_hh  = (const float*)d_in[3];
    const float* b_hh  = (const float*)d_in[4];
    const float* W_out = (const float*)d_in[5];
    const float* b_out = (const float*)d_in[6];
    float* out = (float*)d_out;

    uint32_t* anomw = (ws_size >= 512) ? (uint32_t*)d_ws
                                       : (uint32_t*)(out + (size_t)Bb * Tt);

    anom_kernel<<<64, 256, 0, stream>>>(x, anomw);
    lstm_kernel<<<Bb, 512, 0, stream>>>(x, W_ih, b_ih, W_hh, b_hh, W_out, b_out,
                                        anomw, out);
}